// Round 1
// baseline (925.298 us; speedup 1.0000x reference)
//
#include <hip/hip_runtime.h>
#include <hip/hip_bf16.h>

typedef __bf16 bf16x8 __attribute__((ext_vector_type(8)));
typedef float f32x4 __attribute__((ext_vector_type(4)));

__device__ __forceinline__ unsigned short f2bf(float f) {
  union { float f; unsigned u; } x; x.f = f;
  unsigned r = x.u + 0x7fffu + ((x.u >> 16) & 1u);
  return (unsigned short)(r >> 16);
}

__device__ __forceinline__ void async_ld16(const void* g, void* l) {
  __builtin_amdgcn_global_load_lds(
      (__attribute__((address_space(1))) void*)const_cast<void*>(g),
      (__attribute__((address_space(3))) void*)l, 16, 0, 0);
}

#define BM 128
#define BN 128
#define BK 64

// epilogue modes
#define EPI_X      0  // scale; write f32, bf16, bf16-transposed-per-batch (assumes N=1024, S=2048)
#define EPI_F32    1  // scale; write f32
#define EPI_RELUBF 2  // scale; relu; write bf16

__global__ __launch_bounds__(256) void gemm_bt(
    const unsigned short* __restrict__ A,   // [M][K] bf16 row-major
    const unsigned short* __restrict__ Bt,  // [N][K] bf16 row-major (B transposed)
    int M, int N, int K, float scale, int mode,
    float* __restrict__ outF, unsigned short* __restrict__ outB,
    unsigned short* __restrict__ outT)
{
  __shared__ unsigned short smA[BM * BK];
  __shared__ unsigned short smB[BN * BK];
  const int t = threadIdx.x;
  const int w = t >> 6, l = t & 63;
  const int lr = l & 15, lg = l >> 4;
  const int ntn = N / BN;
  const int bi = blockIdx.x / ntn, bj = blockIdx.x % ntn;
  const int row0 = bi * BM, col0 = bj * BN;
  const int wr = w >> 1, wc = w & 1;  // 2x2 waves, 64x64 each

  f32x4 acc[4][4];
#pragma unroll
  for (int m = 0; m < 4; ++m)
#pragma unroll
    for (int n = 0; n < 4; ++n) acc[m][n] = (f32x4){0.f, 0.f, 0.f, 0.f};

  for (int k0 = 0; k0 < K; k0 += BK) {
    // stage A[128][64] and Bt[128][64] tiles: 4 issues x 256 threads x 16B each
#pragma unroll
    for (int i = 0; i < 4; ++i) {
      int e = (i * 256 + t) * 8;        // element index in [128][64] tile
      int r = e >> 6, c = e & 63;
      async_ld16(A  + (size_t)(row0 + r) * K + (k0 + c), &smA[i * 2048 + w * 512]);
      async_ld16(Bt + (size_t)(col0 + r) * K + (k0 + c), &smB[i * 2048 + w * 512]);
    }
    __syncthreads();
#pragma unroll
    for (int kk = 0; kk < BK; kk += 32) {
      bf16x8 af[4], bfr[4];
#pragma unroll
      for (int m = 0; m < 4; ++m)
        af[m] = *(const bf16x8*)&smA[(wr * 64 + m * 16 + lr) * BK + kk + lg * 8];
#pragma unroll
      for (int n = 0; n < 4; ++n)
        bfr[n] = *(const bf16x8*)&smB[(wc * 64 + n * 16 + lr) * BK + kk + lg * 8];
#pragma unroll
      for (int m = 0; m < 4; ++m)
#pragma unroll
        for (int n = 0; n < 4; ++n)
          acc[m][n] = __builtin_amdgcn_mfma_f32_16x16x32_bf16(af[m], bfr[n], acc[m][n], 0, 0, 0);
    }
    __syncthreads();
  }

  // epilogue: C/D layout col=lane&15, row=(lane>>4)*4+reg  [m89-verified]
#pragma unroll
  for (int m = 0; m < 4; ++m) {
    int rbase = row0 + wr * 64 + m * 16 + lg * 4;
#pragma unroll
    for (int n = 0; n < 4; ++n) {
      int c = col0 + wc * 64 + n * 16 + lr;
      f32x4 v = acc[m][n];
#pragma unroll
      for (int q = 0; q < 4; ++q) {
        int rr = rbase + q;
        float val = v[q] * scale;
        if (mode == EPI_X) {
          outF[(size_t)rr * N + c] = val;
          unsigned short b = f2bf(val);
          outB[(size_t)rr * N + c] = b;
          int bb = rr >> 11, s = rr & 2047;
          outT[((size_t)(bb * 1024 + c) << 11) + s] = b;
        } else if (mode == EPI_F32) {
          outF[(size_t)rr * N + c] = val;
        } else {  // EPI_RELUBF
          outB[(size_t)rr * N + c] = f2bf(fmaxf(val, 0.f));
        }
      }
    }
  }
}

__device__ __forceinline__ float wave_sum(float v) {
#pragma unroll
  for (int o = 32; o; o >>= 1) v += __shfl_xor(v, o, 64);
  return v;
}
__device__ __forceinline__ float wave_max(float v) {
#pragma unroll
  for (int o = 32; o; o >>= 1) v = fmaxf(v, __shfl_xor(v, o, 64));
  return v;
}

// cast f32 -> bf16, vectorized x4
__global__ __launch_bounds__(256) void cast_bf16(const float* __restrict__ in,
                                                 unsigned short* __restrict__ out, long n) {
  long i = ((long)blockIdx.x * 256 + threadIdx.x) * 4;
  if (i >= n) return;
  float4 v = *(const float4*)&in[i];
  ushort4 o;
  o.x = f2bf(v.x); o.y = f2bf(v.y); o.z = f2bf(v.z); o.w = f2bf(v.w);
  *(ushort4*)&out[i] = o;
}

// in[R][C] f32 -> out[C][R] bf16 (tiled)
__global__ __launch_bounds__(256) void transpose_cast(const float* __restrict__ in,
                                                      unsigned short* __restrict__ out,
                                                      int R, int C) {
  __shared__ float tile[32][33];
  int c0 = blockIdx.x * 32, r0 = blockIdx.y * 32;
  int tx = threadIdx.x, ty = threadIdx.y;  // block (32,8)
  for (int i = ty; i < 32; i += 8) tile[i][tx] = in[(size_t)(r0 + i) * C + c0 + tx];
  __syncthreads();
  for (int i = ty; i < 32; i += 8) out[(size_t)(c0 + i) * R + r0 + tx] = f2bf(tile[tx][i]);
}

// softmax over rows of 2048 f32 -> bf16 weights
__global__ __launch_bounds__(256) void softmax_rows(const float* __restrict__ g,
                                                    unsigned short* __restrict__ wout) {
  __shared__ float red[4];
  int row = blockIdx.x, t = threadIdx.x;
  const float* gr = g + ((size_t)row << 11);
  float4 a = *(const float4*)&gr[t * 8];
  float4 b = *(const float4*)&gr[t * 8 + 4];
  float mx = fmaxf(fmaxf(fmaxf(a.x, a.y), fmaxf(a.z, a.w)),
                   fmaxf(fmaxf(b.x, b.y), fmaxf(b.z, b.w)));
  mx = wave_max(mx);
  if ((t & 63) == 0) red[t >> 6] = mx;
  __syncthreads();
  mx = fmaxf(fmaxf(red[0], red[1]), fmaxf(red[2], red[3]));
  float e0 = __expf(a.x - mx), e1 = __expf(a.y - mx), e2 = __expf(a.z - mx), e3 = __expf(a.w - mx);
  float e4 = __expf(b.x - mx), e5 = __expf(b.y - mx), e6 = __expf(b.z - mx), e7 = __expf(b.w - mx);
  float s = ((e0 + e1) + (e2 + e3)) + ((e4 + e5) + (e6 + e7));
  s = wave_sum(s);
  __syncthreads();
  if ((t & 63) == 0) red[t >> 6] = s;
  __syncthreads();
  s = (red[0] + red[1]) + (red[2] + red[3]);
  float inv = 1.0f / s;
  ushort4 o0, o1;
  o0.x = f2bf(e0 * inv); o0.y = f2bf(e1 * inv); o0.z = f2bf(e2 * inv); o0.w = f2bf(e3 * inv);
  o1.x = f2bf(e4 * inv); o1.y = f2bf(e5 * inv); o1.z = f2bf(e6 * inv); o1.w = f2bf(e7 * inv);
  size_t base = ((size_t)row << 11) + t * 8;
  *(ushort4*)&wout[base] = o0;
  *(ushort4*)&wout[base + 4] = o1;
}

// layernorm(a+b) over rows of 1024, ddof=1, no eps -> f32 + bf16
__global__ __launch_bounds__(256) void ln_residual(const float* __restrict__ xa,
                                                   const float* __restrict__ xb,
                                                   float* __restrict__ outF,
                                                   unsigned short* __restrict__ outB) {
  __shared__ float red[4];
  int row = blockIdx.x, t = threadIdx.x;
  size_t base = ((size_t)row << 10) + t * 4;
  float4 va = *(const float4*)&xa[base];
  float4 vb = *(const float4*)&xb[base];
  float4 v = {va.x + vb.x, va.y + vb.y, va.z + vb.z, va.w + vb.w};
  float s = (v.x + v.y) + (v.z + v.w);
  float ss = (v.x * v.x + v.y * v.y) + (v.z * v.z + v.w * v.w);
  s = wave_sum(s);
  if ((t & 63) == 0) red[t >> 6] = s;
  __syncthreads();
  s = (red[0] + red[1]) + (red[2] + red[3]);
  ss = wave_sum(ss);
  __syncthreads();
  if ((t & 63) == 0) red[t >> 6] = ss;
  __syncthreads();
  ss = (red[0] + red[1]) + (red[2] + red[3]);
  float mean = s * (1.0f / 1024.0f);
  float var = (ss - s * mean) * (1.0f / 1023.0f);
  float rstd = rsqrtf(var);
  float4 o = {(v.x - mean) * rstd, (v.y - mean) * rstd, (v.z - mean) * rstd, (v.w - mean) * rstd};
  *(float4*)&outF[base] = o;
  ushort4 ob;
  ob.x = f2bf(o.x); ob.y = f2bf(o.y); ob.z = f2bf(o.z); ob.w = f2bf(o.w);
  *(ushort4*)&outB[base] = ob;
}

// layernorm(a+b) then dot with readout -> rowdot[row]
__global__ __launch_bounds__(256) void ln_residual_dot(const float* __restrict__ xa,
                                                       const float* __restrict__ xb,
                                                       const float* __restrict__ readout,
                                                       float* __restrict__ rowdot) {
  __shared__ float red[4];
  int row = blockIdx.x, t = threadIdx.x;
  size_t base = ((size_t)row << 10) + t * 4;
  float4 va = *(const float4*)&xa[base];
  float4 vb = *(const float4*)&xb[base];
  float4 v = {va.x + vb.x, va.y + vb.y, va.z + vb.z, va.w + vb.w};
  float s = (v.x + v.y) + (v.z + v.w);
  float ss = (v.x * v.x + v.y * v.y) + (v.z * v.z + v.w * v.w);
  s = wave_sum(s);
  if ((t & 63) == 0) red[t >> 6] = s;
  __syncthreads();
  s = (red[0] + red[1]) + (red[2] + red[3]);
  ss = wave_sum(ss);
  __syncthreads();
  if ((t & 63) == 0) red[t >> 6] = ss;
  __syncthreads();
  ss = (red[0] + red[1]) + (red[2] + red[3]);
  float mean = s * (1.0f / 1024.0f);
  float var = (ss - s * mean) * (1.0f / 1023.0f);
  float rstd = rsqrtf(var);
  float4 r = *(const float4*)&readout[t * 4];
  float dot = (v.x - mean) * rstd * r.x + (v.y - mean) * rstd * r.y +
              (v.z - mean) * rstd * r.z + (v.w - mean) * rstd * r.w;
  dot = wave_sum(dot);
  __syncthreads();
  if ((t & 63) == 0) red[t >> 6] = dot;
  __syncthreads();
  if (t == 0) rowdot[row] = (red[0] + red[1]) + (red[2] + red[3]);
}

// out[b] = sum(rowdot[b*2048 .. +2048]) / (2048 * 32)
__global__ __launch_bounds__(256) void reduce_out(const float* __restrict__ rowdot,
                                                  float* __restrict__ out) {
  __shared__ float red[4];
  int b = blockIdx.x, t = threadIdx.x;
  float s = 0.f;
  for (int i = t; i < 2048; i += 256) s += rowdot[(size_t)b * 2048 + i];
  s = wave_sum(s);
  if ((t & 63) == 0) red[t >> 6] = s;
  __syncthreads();
  if (t == 0) out[b] = ((red[0] + red[1]) + (red[2] + red[3])) * (1.0f / 65536.0f);
}

extern "C" void kernel_launch(void* const* d_in, const int* in_sizes, int n_in,
                              void* d_out, int out_size, void* d_ws, size_t ws_size,
                              hipStream_t stream) {
  const float* seq     = (const float*)d_in[0];  // [8,2048,768]
  const float* emb     = (const float*)d_in[1];  // [768,1024]
  const float* W1      = (const float*)d_in[2];  // [1024,1024]
  const float* W2      = (const float*)d_in[3];  // [1024,1024]
  const float* readout = (const float*)d_in[4];  // [1024]
  float* out = (float*)d_out;                    // [8]

  char* ws = (char*)d_ws;
  const size_t MB = 1024u * 1024u;
  // aliased layout (phases are strictly sequential on `stream`):
  float*          x_f32  = (float*)(ws + 0);            // 64MB; dead after LN1
  unsigned short* hrelu  = (unsigned short*)(ws + 0);   // 32MB; written by GEMM4 (after LN1)
  unsigned short* seq_b  = (unsigned short*)(ws + 64 * MB);  // 24MB; dead after GEMM1
  float*          attn   = (float*)(ws + 64 * MB);      // 64MB; dead after LN1
  float*          h2     = (float*)(ws + 64 * MB);      // 64MB; written by GEMM5 (after LN1)
  float*          gram   = (float*)(ws + 128 * MB);     // 16MB; per-batch, dead after loop
  unsigned short* wts    = (unsigned short*)(ws + 144 * MB); // 8MB; per-batch
  unsigned short* x_b    = (unsigned short*)(ws + 152 * MB); // 32MB; dead after loop
  unsigned short* xT     = (unsigned short*)(ws + 184 * MB); // 32MB; dead after loop
  float*          post   = (float*)(ws + 128 * MB);     // 64MB; written by LN1 over gram/wts/x_b/xT-head
  unsigned short* post_b = (unsigned short*)(ws + 192 * MB); // 32MB; written by LN1 over xT-tail
  unsigned short* embT   = (unsigned short*)(ws + 224 * MB); // 1.5MB
  unsigned short* W1T    = (unsigned short*)(ws + 226 * MB); // 2MB
  unsigned short* W2T    = (unsigned short*)(ws + 228 * MB); // 2MB
  float*          rowdot = (float*)(ws + 230 * MB);     // 64KB  (total ~230.1MB)

  // 1. dtype prep
  cast_bf16<<<12288, 256, 0, stream>>>(seq, seq_b, 12582912L);
  transpose_cast<<<dim3(32, 24), dim3(32, 8), 0, stream>>>(emb, embT, 768, 1024);
  transpose_cast<<<dim3(32, 32), dim3(32, 8), 0, stream>>>(W1, W1T, 1024, 1024);
  transpose_cast<<<dim3(32, 32), dim3(32, 8), 0, stream>>>(W2, W2T, 1024, 1024);

  // 2. x = seq @ emb / sqrt(768): writes x_f32, x_b (bf16), xT (bf16, per-batch transposed)
  gemm_bt<<<1024, 256, 0, stream>>>(seq_b, embT, 16384, 1024, 768,
                                    0.03608439182435161f, EPI_X, x_f32, x_b, xT);

  // 3. per-batch: gram -> softmax -> attn
  for (int b = 0; b < 8; ++b) {
    const unsigned short* xb = x_b + (size_t)b * 2048 * 1024;
    gemm_bt<<<256, 256, 0, stream>>>(xb, xb, 2048, 2048, 1024,
                                     1.0f / 1024.0f, EPI_F32, gram, nullptr, nullptr);
    softmax_rows<<<2048, 256, 0, stream>>>(gram, wts);
    gemm_bt<<<128, 256, 0, stream>>>(wts, xT + (size_t)b * 1024 * 2048, 2048, 1024, 2048,
                                     1.0f, EPI_F32, attn + (size_t)b * 2048 * 1024,
                                     nullptr, nullptr);
  }

  // 4. post_attn = LN(x + attn)
  ln_residual<<<16384, 256, 0, stream>>>(x_f32, attn, post, post_b);

  // 5. FFN: h = relu(post @ W1 / 32) ; h2 = h @ W2 / 32
  gemm_bt<<<1024, 256, 0, stream>>>(post_b, W1T, 16384, 1024, 1024,
                                    0.03125f, EPI_RELUBF, nullptr, hrelu, nullptr);
  gemm_bt<<<1024, 256, 0, stream>>>(hrelu, W2T, 16384, 1024, 1024,
                                    0.03125f, EPI_F32, h2, nullptr, nullptr);

  // 6. final LN + pooled readout (deterministic two-stage reduction)
  ln_residual_dot<<<16384, 256, 0, stream>>>(h2, post, readout, rowdot);
  reduce_out<<<8, 256, 0, stream>>>(rowdot, out);
}

// Round 3
// 518.888 us; speedup vs baseline: 1.7832x; 1.7832x over previous
//
#include <hip/hip_runtime.h>
#include <hip/hip_bf16.h>

typedef __bf16 bf16x8 __attribute__((ext_vector_type(8)));
typedef float f32x4 __attribute__((ext_vector_type(4)));

__device__ __forceinline__ unsigned short f2bf(float f) {
  union { float f; unsigned u; } x; x.f = f;
  unsigned r = x.u + 0x7fffu + ((x.u >> 16) & 1u);
  return (unsigned short)(r >> 16);
}
__device__ __forceinline__ float bf2f(unsigned short u) {
  union { unsigned u; float f; } x; x.u = (unsigned)u << 16;
  return x.f;
}
__device__ __forceinline__ unsigned short f2h(float f) {
  union { _Float16 h; unsigned short u; } x; x.h = (_Float16)f;
  return x.u;
}
__device__ __forceinline__ float h2f(unsigned short u) {
  union { _Float16 h; unsigned short u; } x; x.u = u;
  return (float)x.h;
}

__device__ __forceinline__ void async_ld16(const void* g, void* l) {
  __builtin_amdgcn_global_load_lds(
      (__attribute__((address_space(1))) void*)const_cast<void*>(g),
      (__attribute__((address_space(3))) void*)l, 16, 0, 0);
}

#define BM 128
#define BN 128
#define BK 64

// epilogue modes
#define EPI_F32    0  // scale; write f32
#define EPI_BF     1  // scale; write bf16
#define EPI_RELUBF 2  // scale; relu; write bf16
#define EPI_F16    3  // scale; write f16

// C = A @ Bt^T, batched. A:[nb][M][K] bf16, Bt:[nb][N][K] bf16, out:[nb][M][N].
// grid.x = nbatch * (M/BM) * (N/BN); bijective chunked XCD swizzle (grid % 8 == 0).
__global__ __launch_bounds__(256) void gemm_bt(
    const unsigned short* __restrict__ A,
    const unsigned short* __restrict__ Bt,
    int M, int N, int K, int nbatch,
    long sA, long sB, long sC,
    float scale, int mode, void* __restrict__ outp)
{
  __shared__ unsigned short smA[BM * BK];
  __shared__ unsigned short smB[BN * BK];
  const int t = threadIdx.x;
  const int w = t >> 6, l = t & 63;
  const int lr = l & 15, lg = l >> 4;
  const int ntn = N / BN;
  const int tiles = (M / BM) * ntn;
  const int chunk = (tiles * nbatch) >> 3;
  const int bid = blockIdx.x;
  const int wg = (bid & 7) * chunk + (bid >> 3);
  const int batch = wg / tiles;
  const int rem = wg - batch * tiles;
  const int bi = rem / ntn, bj = rem % ntn;
  const int row0 = bi * BM, col0 = bj * BN;
  const int wr = w >> 1, wc = w & 1;  // 2x2 waves, 64x64 each

  A  += (long)batch * sA;
  Bt += (long)batch * sB;

  f32x4 acc[4][4];
#pragma unroll
  for (int m = 0; m < 4; ++m)
#pragma unroll
    for (int n = 0; n < 4; ++n) acc[m][n] = (f32x4){0.f, 0.f, 0.f, 0.f};

  for (int k0 = 0; k0 < K; k0 += BK) {
#pragma unroll
    for (int i = 0; i < 4; ++i) {
      int e = (i * 256 + t) * 8;  // element index in [128][64] tile
      int r = e >> 6, c = e & 63;
      async_ld16(A  + (size_t)(row0 + r) * K + (k0 + c), &smA[i * 2048 + w * 512]);
      async_ld16(Bt + (size_t)(col0 + r) * K + (k0 + c), &smB[i * 2048 + w * 512]);
    }
    __syncthreads();
#pragma unroll
    for (int kk = 0; kk < BK; kk += 32) {
      bf16x8 af[4], bfr[4];
#pragma unroll
      for (int m = 0; m < 4; ++m)
        af[m] = *(const bf16x8*)&smA[(wr * 64 + m * 16 + lr) * BK + kk + lg * 8];
#pragma unroll
      for (int n = 0; n < 4; ++n)
        bfr[n] = *(const bf16x8*)&smB[(wc * 64 + n * 16 + lr) * BK + kk + lg * 8];
#pragma unroll
      for (int m = 0; m < 4; ++m)
#pragma unroll
        for (int n = 0; n < 4; ++n)
          acc[m][n] = __builtin_amdgcn_mfma_f32_16x16x32_bf16(af[m], bfr[n], acc[m][n], 0, 0, 0);
    }
    __syncthreads();
  }

  float* outF = (float*)outp;
  unsigned short* outH = (unsigned short*)outp;
  const size_t cb = (size_t)batch * (size_t)sC;
#pragma unroll
  for (int m = 0; m < 4; ++m) {
    int rbase = row0 + wr * 64 + m * 16 + lg * 4;
#pragma unroll
    for (int n = 0; n < 4; ++n) {
      int c = col0 + wc * 64 + n * 16 + lr;
      f32x4 v = acc[m][n];
#pragma unroll
      for (int q = 0; q < 4; ++q) {
        size_t idx = cb + (size_t)(rbase + q) * N + c;
        float val = v[q] * scale;
        if (mode == EPI_F32)        outF[idx] = val;
        else if (mode == EPI_BF)    outH[idx] = f2bf(val);
        else if (mode == EPI_RELUBF) outH[idx] = f2bf(fmaxf(val, 0.f));
        else                        outH[idx] = f2h(val);
      }
    }
  }
}

__device__ __forceinline__ float wave_sum(float v) {
#pragma unroll
  for (int o = 32; o; o >>= 1) v += __shfl_xor(v, o, 64);
  return v;
}
__device__ __forceinline__ float wave_max(float v) {
#pragma unroll
  for (int o = 32; o; o >>= 1) v = fmaxf(v, __shfl_xor(v, o, 64));
  return v;
}

__global__ __launch_bounds__(256) void cast_bf16(const float* __restrict__ in,
                                                 unsigned short* __restrict__ out, long n) {
  long i = ((long)blockIdx.x * 256 + threadIdx.x) * 4;
  if (i >= n) return;
  float4 v = *(const float4*)&in[i];
  ushort4 o;
  o.x = f2bf(v.x); o.y = f2bf(v.y); o.z = f2bf(v.z); o.w = f2bf(v.w);
  *(ushort4*)&out[i] = o;
}

// in[R][C] f32 -> out[C][R] bf16 (tiled)
__global__ __launch_bounds__(256) void transpose_cast(const float* __restrict__ in,
                                                      unsigned short* __restrict__ out,
                                                      int R, int C) {
  __shared__ float tile[32][33];
  int c0 = blockIdx.x * 32, r0 = blockIdx.y * 32;
  int tx = threadIdx.x, ty = threadIdx.y;  // block (32,8)
  for (int i = ty; i < 32; i += 8) tile[i][tx] = in[(size_t)(r0 + i) * C + c0 + tx];
  __syncthreads();
  for (int i = ty; i < 32; i += 8) out[(size_t)(c0 + i) * R + r0 + tx] = f2bf(tile[tx][i]);
}

// per-batch bf16 transpose: in[z][R][C] -> out[z][C][R]
__global__ __launch_bounds__(256) void transpose_b16(const unsigned short* __restrict__ in,
                                                     unsigned short* __restrict__ out,
                                                     int R, int C) {
  __shared__ unsigned short tile[32][33];
  int c0 = blockIdx.x * 32, r0 = blockIdx.y * 32;
  size_t zb = (size_t)blockIdx.z * R * C;
  int tx = threadIdx.x, ty = threadIdx.y;  // block (32,8)
  for (int i = ty; i < 32; i += 8) tile[i][tx] = in[zb + (size_t)(r0 + i) * C + c0 + tx];
  __syncthreads();
  for (int i = ty; i < 32; i += 8) out[zb + (size_t)(c0 + i) * R + r0 + tx] = tile[tx][i];
}

// softmax over rows of 2048 (f16 in) -> bf16 weights
__global__ __launch_bounds__(256) void softmax_rows(const unsigned short* __restrict__ g,
                                                    unsigned short* __restrict__ wout) {
  __shared__ float red[4];
  int row = blockIdx.x, t = threadIdx.x;
  const unsigned short* gr = g + ((size_t)row << 11) + t * 8;
  ushort4 ua = *(const ushort4*)gr;
  ushort4 ub = *(const ushort4*)(gr + 4);
  float a0 = h2f(ua.x), a1 = h2f(ua.y), a2 = h2f(ua.z), a3 = h2f(ua.w);
  float b0 = h2f(ub.x), b1 = h2f(ub.y), b2 = h2f(ub.z), b3 = h2f(ub.w);
  float mx = fmaxf(fmaxf(fmaxf(a0, a1), fmaxf(a2, a3)),
                   fmaxf(fmaxf(b0, b1), fmaxf(b2, b3)));
  mx = wave_max(mx);
  if ((t & 63) == 0) red[t >> 6] = mx;
  __syncthreads();
  mx = fmaxf(fmaxf(red[0], red[1]), fmaxf(red[2], red[3]));
  float e0 = __expf(a0 - mx), e1 = __expf(a1 - mx), e2 = __expf(a2 - mx), e3 = __expf(a3 - mx);
  float e4 = __expf(b0 - mx), e5 = __expf(b1 - mx), e6 = __expf(b2 - mx), e7 = __expf(b3 - mx);
  float s = ((e0 + e1) + (e2 + e3)) + ((e4 + e5) + (e6 + e7));
  s = wave_sum(s);
  __syncthreads();
  if ((t & 63) == 0) red[t >> 6] = s;
  __syncthreads();
  s = (red[0] + red[1]) + (red[2] + red[3]);
  float inv = 1.0f / s;
  ushort4 o0, o1;
  o0.x = f2bf(e0 * inv); o0.y = f2bf(e1 * inv); o0.z = f2bf(e2 * inv); o0.w = f2bf(e3 * inv);
  o1.x = f2bf(e4 * inv); o1.y = f2bf(e5 * inv); o1.z = f2bf(e6 * inv); o1.w = f2bf(e7 * inv);
  size_t base = ((size_t)row << 11) + t * 8;
  *(ushort4*)&wout[base] = o0;
  *(ushort4*)&wout[base + 4] = o1;
}

// post = LN(x_b + attn), ddof=1; write bf16 only
__global__ __launch_bounds__(256) void ln_residual_bf(const unsigned short* __restrict__ xb,
                                                      const float* __restrict__ attn,
                                                      unsigned short* __restrict__ outB) {
  __shared__ float red[4];
  int row = blockIdx.x, t = threadIdx.x;
  size_t base = ((size_t)row << 10) + t * 4;
  ushort4 ua = *(const ushort4*)&xb[base];
  float4 vb = *(const float4*)&attn[base];
  float4 v = {bf2f(ua.x) + vb.x, bf2f(ua.y) + vb.y, bf2f(ua.z) + vb.z, bf2f(ua.w) + vb.w};
  float s = (v.x + v.y) + (v.z + v.w);
  float ss = (v.x * v.x + v.y * v.y) + (v.z * v.z + v.w * v.w);
  s = wave_sum(s);
  if ((t & 63) == 0) red[t >> 6] = s;
  __syncthreads();
  s = (red[0] + red[1]) + (red[2] + red[3]);
  ss = wave_sum(ss);
  __syncthreads();
  if ((t & 63) == 0) red[t >> 6] = ss;
  __syncthreads();
  ss = (red[0] + red[1]) + (red[2] + red[3]);
  float mean = s * (1.0f / 1024.0f);
  float var = (ss - s * mean) * (1.0f / 1023.0f);
  float rstd = rsqrtf(var);
  ushort4 ob;
  ob.x = f2bf((v.x - mean) * rstd); ob.y = f2bf((v.y - mean) * rstd);
  ob.z = f2bf((v.z - mean) * rstd); ob.w = f2bf((v.w - mean) * rstd);
  *(ushort4*)&outB[base] = ob;
}

// rowdot[row] = LN(h2 + post) . readout   (both inputs bf16)
__global__ __launch_bounds__(256) void ln_residual_dot(const unsigned short* __restrict__ h2,
                                                       const unsigned short* __restrict__ post,
                                                       const float* __restrict__ readout,
                                                       float* __restrict__ rowdot) {
  __shared__ float red[4];
  int row = blockIdx.x, t = threadIdx.x;
  size_t base = ((size_t)row << 10) + t * 4;
  ushort4 ua = *(const ushort4*)&h2[base];
  ushort4 ub = *(const ushort4*)&post[base];
  float4 v = {bf2f(ua.x) + bf2f(ub.x), bf2f(ua.y) + bf2f(ub.y),
              bf2f(ua.z) + bf2f(ub.z), bf2f(ua.w) + bf2f(ub.w)};
  float s = (v.x + v.y) + (v.z + v.w);
  float ss = (v.x * v.x + v.y * v.y) + (v.z * v.z + v.w * v.w);
  s = wave_sum(s);
  if ((t & 63) == 0) red[t >> 6] = s;
  __syncthreads();
  s = (red[0] + red[1]) + (red[2] + red[3]);
  ss = wave_sum(ss);
  __syncthreads();
  if ((t & 63) == 0) red[t >> 6] = ss;
  __syncthreads();
  ss = (red[0] + red[1]) + (red[2] + red[3]);
  float mean = s * (1.0f / 1024.0f);
  float var = (ss - s * mean) * (1.0f / 1023.0f);
  float rstd = rsqrtf(var);
  float4 r = *(const float4*)&readout[t * 4];
  float dot = (v.x - mean) * rstd * r.x + (v.y - mean) * rstd * r.y +
              (v.z - mean) * rstd * r.z + (v.w - mean) * rstd * r.w;
  dot = wave_sum(dot);
  __syncthreads();
  if ((t & 63) == 0) red[t >> 6] = dot;
  __syncthreads();
  if (t == 0) rowdot[row] = (red[0] + red[1]) + (red[2] + red[3]);
}

__global__ __launch_bounds__(256) void reduce_out(const float* __restrict__ rowdot,
                                                  float* __restrict__ out) {
  __shared__ float red[4];
  int b = blockIdx.x, t = threadIdx.x;
  float s = 0.f;
  for (int i = t; i < 2048; i += 256) s += rowdot[(size_t)b * 2048 + i];
  s = wave_sum(s);
  if ((t & 63) == 0) red[t >> 6] = s;
  __syncthreads();
  if (t == 0) out[b] = ((red[0] + red[1]) + (red[2] + red[3])) * (1.0f / 65536.0f);
}

extern "C" void kernel_launch(void* const* d_in, const int* in_sizes, int n_in,
                              void* d_out, int out_size, void* d_ws, size_t ws_size,
                              hipStream_t stream) {
  const float* seq     = (const float*)d_in[0];  // [8,2048,768]
  const float* emb     = (const float*)d_in[1];  // [768,1024]
  const float* W1      = (const float*)d_in[2];  // [1024,1024]
  const float* W2      = (const float*)d_in[3];  // [1024,1024]
  const float* readout = (const float*)d_in[4];  // [1024]
  float* out = (float*)d_out;                    // [8]

  char* ws = (char*)d_ws;
  const size_t MB = 1024u * 1024u;
  // aliased layout (phases strictly sequential on `stream`).
  // Lifetimes:  x_b [G1..LN1] | h2b [FFN2..LN2]      @ 0   (32MB)
  //             xT [tr..attnV] | hrelu [FFN1..FFN2]  @ 32  (32MB)
  //             gram f16 [G2..sm] | attn f32 [aV..LN1] @ 64 (64MB)
  //             wts [sm..attnV] (64MB!) | post_b [LN1..LN2] @ 128 (64MB)
  //             seq_b [cast..G1]                     @ 192 (24MB)
  //             embT/W1T/W2T/rowdot                  @ 216.. (~6MB)
  unsigned short* x_b    = (unsigned short*)(ws + 0);
  unsigned short* h2b    = (unsigned short*)(ws + 0);
  unsigned short* xT     = (unsigned short*)(ws + 32 * MB);
  unsigned short* hrelu  = (unsigned short*)(ws + 32 * MB);
  unsigned short* gram   = (unsigned short*)(ws + 64 * MB);
  float*          attn   = (float*)(ws + 64 * MB);
  unsigned short* wts    = (unsigned short*)(ws + 128 * MB);
  unsigned short* post_b = (unsigned short*)(ws + 128 * MB);
  unsigned short* seq_b  = (unsigned short*)(ws + 192 * MB);
  unsigned short* embT   = (unsigned short*)(ws + 216 * MB);
  unsigned short* W1T    = (unsigned short*)(ws + 218 * MB);
  unsigned short* W2T    = (unsigned short*)(ws + 220 * MB);
  float*          rowdot = (float*)(ws + 222 * MB);

  // 1. dtype prep
  cast_bf16<<<12288, 256, 0, stream>>>(seq, seq_b, 12582912L);
  transpose_cast<<<dim3(32, 24), dim3(32, 8), 0, stream>>>(emb, embT, 768, 1024);
  transpose_cast<<<dim3(32, 32), dim3(32, 8), 0, stream>>>(W1, W1T, 1024, 1024);
  transpose_cast<<<dim3(32, 32), dim3(32, 8), 0, stream>>>(W2, W2T, 1024, 1024);

  // 2. x = seq @ emb / sqrt(768)  -> bf16
  gemm_bt<<<1024, 256, 0, stream>>>(seq_b, embT, 16384, 1024, 768, 1, 0, 0, 0,
                                    0.03608439182435161f, EPI_BF, x_b);

  // 3. xT[b] = x[b]^T (coalesced, per-batch)
  transpose_b16<<<dim3(32, 64, 8), dim3(32, 8), 0, stream>>>(x_b, xT, 2048, 1024);

  // 4. gram[b] = x[b] @ x[b]^T / 1024  -> f16   (one batch per XCD)
  gemm_bt<<<2048, 256, 0, stream>>>(x_b, x_b, 2048, 2048, 1024, 8,
                                    2048L * 1024, 2048L * 1024, 2048L * 2048,
                                    1.0f / 1024.0f, EPI_F16, gram);

  // 5. weights = softmax(gram)  -> bf16
  softmax_rows<<<16384, 256, 0, stream>>>(gram, wts);

  // 6. attn[b] = weights[b] @ x[b]  -> f32
  gemm_bt<<<1024, 256, 0, stream>>>(wts, xT, 2048, 1024, 2048, 8,
                                    2048L * 2048, 1024L * 2048, 2048L * 1024,
                                    1.0f, EPI_F32, attn);

  // 7. post = LN(x + attn) -> bf16
  ln_residual_bf<<<16384, 256, 0, stream>>>(x_b, attn, post_b);

  // 8. FFN
  gemm_bt<<<1024, 256, 0, stream>>>(post_b, W1T, 16384, 1024, 1024, 1, 0, 0, 0,
                                    0.03125f, EPI_RELUBF, hrelu);
  gemm_bt<<<1024, 256, 0, stream>>>(hrelu, W2T, 16384, 1024, 1024, 1, 0, 0, 0,
                                    0.03125f, EPI_BF, h2b);

  // 9. final LN + pooled readout
  ln_residual_dot<<<16384, 256, 0, stream>>>(h2b, post_b, readout, rowdot);
  reduce_out<<<8, 256, 0, stream>>>(rowdot, out);
}

// Round 4
// 430.502 us; speedup vs baseline: 2.1493x; 1.2053x over previous
//
#include <hip/hip_runtime.h>
#include <hip/hip_bf16.h>

typedef __bf16 bf16x8 __attribute__((ext_vector_type(8)));
typedef float f32x4 __attribute__((ext_vector_type(4)));

__device__ __forceinline__ unsigned short f2bf(float f) {
  union { float f; unsigned u; } x; x.f = f;
  unsigned r = x.u + 0x7fffu + ((x.u >> 16) & 1u);
  return (unsigned short)(r >> 16);
}
__device__ __forceinline__ float bf2f(unsigned short u) {
  union { unsigned u; float f; } x; x.u = (unsigned)u << 16;
  return x.f;
}
__device__ __forceinline__ unsigned short f2h(float f) {
  union { _Float16 h; unsigned short u; } x; x.h = (_Float16)f;
  return x.u;
}
__device__ __forceinline__ float h2f(unsigned short u) {
  union { _Float16 h; unsigned short u; } x; x.u = u;
  return (float)x.h;
}

__device__ __forceinline__ void async_ld16(const void* g, void* l) {
  __builtin_amdgcn_global_load_lds(
      (__attribute__((address_space(1))) void*)const_cast<void*>(g),
      (__attribute__((address_space(3))) void*)l, 16, 0, 0);
}

// ---------------- 3-buffer pipelined GEMM ----------------
// BM=256 x BN=128, BK=64, 512 threads (8 waves: 4M x 2N), per-wave 64x64 out.
// LDS: 3 K-tile buffers x (A 256x64 + B 128x64) bf16 = 3 x 48KB = 144KB.
// Stage tile t+2 during tile t's 2 phases (A: 4 gload_lds/wave, B: 2).
// Counted s_waitcnt vmcnt(6) once per K-tile (never 0 in steady state);
// raw s_barrier (no implicit vmcnt drain); setprio(1) around MFMA clusters.
// LDS swizzle: slot(row, c^(row&7)) via pre-swizzled per-lane GLOBAL source
// (linear LDS dest required by global_load_lds) + same XOR on ds_read addr.
// Race-freedom: buffer b is written for tile t+3 only by stage-issues that
// execute after the end-of-tile-t barrier, which follows all tile-t reads.

#define EPI_F32    0
#define EPI_BF     1
#define EPI_RELUBF 2
#define EPI_F16    3

__global__ __launch_bounds__(512, 2) void gemm_bt(
    const unsigned short* __restrict__ A,   // [nb][M][K] bf16
    const unsigned short* __restrict__ Bt,  // [nb][N][K] bf16
    int M, int N, int K, int nbatch,
    long sA, long sB, long sC,
    float scale, int mode, void* __restrict__ outp)
{
  __shared__ unsigned short lds[73728];  // 147456 B = 3 x (16384 A + 8192 B) elems
  const int t = threadIdx.x;
  const int w = t >> 6, l = t & 63;
  const int lr = l & 15, lg = l >> 4;
  const int wr = w >> 1, wc = w & 1;           // 4 M-waves x 2 N-waves
  const int ntn = N >> 7;                      // N/128
  const int tiles = (M >> 8) * ntn;            // per batch
  const int chunk = (tiles * nbatch) >> 3;
  const int bid = blockIdx.x;
  const int wg = (bid & 7) * chunk + (bid >> 3);
  const int batch = wg / tiles;
  const int rem = wg - batch * tiles;
  const int row0 = (rem / ntn) << 8;
  const int col0 = (rem % ntn) << 7;

  const unsigned short* Ab  = A  + (long)batch * sA;
  const unsigned short* Btb = Bt + (long)batch * sB;

  // staging geometry (per thread): covers 16B at swizzled source column
  const int rsub = t >> 3;                       // 0..63 row-in-64-group
  const int cg8  = ((t & 7) ^ (rsub & 7)) << 3;  // swizzled k-chunk offset (elems)
  const long arow = (long)(row0 + rsub) * K;
  const long brow = (long)(col0 + rsub) * K;
  const long rstep = (long)K << 6;               // 64 rows

  const int NT = K >> 6;

#define STAGE_A(buf, kk0)                                                   \
  {                                                                         \
    const unsigned short* s = Ab + arow + (kk0) + cg8;                      \
    unsigned short* d = (buf) + t * 8;                                      \
    async_ld16(s,             d);                                           \
    async_ld16(s + rstep,     d + 4096);                                    \
    async_ld16(s + 2 * rstep, d + 8192);                                    \
    async_ld16(s + 3 * rstep, d + 12288);                                   \
  }
#define STAGE_B(buf, kk0)                                                   \
  {                                                                         \
    const unsigned short* s = Btb + brow + (kk0) + cg8;                     \
    unsigned short* d = (buf) + 16384 + t * 8;                              \
    async_ld16(s,         d);                                               \
    async_ld16(s + rstep, d + 4096);                                        \
  }

  f32x4 acc[4][4];
#pragma unroll
  for (int m = 0; m < 4; ++m)
#pragma unroll
    for (int n = 0; n < 4; ++n) acc[m][n] = (f32x4){0.f, 0.f, 0.f, 0.f};

  // prologue: stage tiles 0 and 1; wait for tile 0 (6 newest = tile 1 in flight)
  STAGE_A(lds, 0); STAGE_B(lds, 0);
  STAGE_A(lds + 24576, 64); STAGE_B(lds + 24576, 64);
  asm volatile("s_waitcnt vmcnt(6)" ::: "memory");
  __builtin_amdgcn_s_barrier();
  __builtin_amdgcn_sched_barrier(0);

  for (int tt = 0; tt < NT; ++tt) {
    unsigned short* ldsA = lds + (tt % 3) * 24576;
    unsigned short* ldsB = ldsA + 16384;
    unsigned short* ldsN = lds + ((tt + 2) % 3) * 24576;
    const bool st = (tt + 2) < NT;
    const int kn = (tt + 2) << 6;

    // ---- phase 0: stage A(t+2); read A frags + B frags (nh=0); MFMA quad 0
    if (st) STAGE_A(ldsN, kn);
    bf16x8 af[4][2], bfr[2][2];
#pragma unroll
    for (int mf = 0; mf < 4; ++mf) {
      int Ra = wr * 64 + mf * 16 + lr;
      int rb = Ra * 64, sw = (Ra & 7) << 3;
      af[mf][0] = *(const bf16x8*)&ldsA[rb + ((lg << 3) ^ sw)];
      af[mf][1] = *(const bf16x8*)&ldsA[rb + (((4 + lg) << 3) ^ sw)];
    }
#pragma unroll
    for (int n = 0; n < 2; ++n) {
      int Rb = wc * 64 + n * 16 + lr;
      int rb = Rb * 64, sw = (Rb & 7) << 3;
      bfr[n][0] = *(const bf16x8*)&ldsB[rb + ((lg << 3) ^ sw)];
      bfr[n][1] = *(const bf16x8*)&ldsB[rb + (((4 + lg) << 3) ^ sw)];
    }
    __builtin_amdgcn_sched_barrier(0);
    __builtin_amdgcn_s_barrier();
    __builtin_amdgcn_sched_barrier(0);
    __builtin_amdgcn_s_setprio(1);
#pragma unroll
    for (int kk = 0; kk < 2; ++kk)
#pragma unroll
      for (int mf = 0; mf < 4; ++mf)
#pragma unroll
        for (int n = 0; n < 2; ++n)
          acc[mf][n] = __builtin_amdgcn_mfma_f32_16x16x32_bf16(af[mf][kk], bfr[n][kk], acc[mf][n], 0, 0, 0);
    __builtin_amdgcn_s_setprio(0);
    __builtin_amdgcn_sched_barrier(0);
    __builtin_amdgcn_s_barrier();
    __builtin_amdgcn_sched_barrier(0);

    // ---- phase 1: stage B(t+2); read B frags (nh=1); vmcnt gate; MFMA quad 1
    if (st) STAGE_B(ldsN, kn);
#pragma unroll
    for (int n = 0; n < 2; ++n) {
      int Rb = wc * 64 + (2 + n) * 16 + lr;
      int rb = Rb * 64, sw = (Rb & 7) << 3;
      bfr[n][0] = *(const bf16x8*)&ldsB[rb + ((lg << 3) ^ sw)];
      bfr[n][1] = *(const bf16x8*)&ldsB[rb + (((4 + lg) << 3) ^ sw)];
    }
    if (st) { asm volatile("s_waitcnt vmcnt(6)" ::: "memory"); }
    else    { asm volatile("s_waitcnt vmcnt(0)" ::: "memory"); }
    __builtin_amdgcn_sched_barrier(0);
    __builtin_amdgcn_s_barrier();
    __builtin_amdgcn_sched_barrier(0);
    __builtin_amdgcn_s_setprio(1);
#pragma unroll
    for (int kk = 0; kk < 2; ++kk)
#pragma unroll
      for (int mf = 0; mf < 4; ++mf)
#pragma unroll
        for (int n = 0; n < 2; ++n)
          acc[mf][2 + n] = __builtin_amdgcn_mfma_f32_16x16x32_bf16(af[mf][kk], bfr[n][kk], acc[mf][2 + n], 0, 0, 0);
    __builtin_amdgcn_s_setprio(0);
    __builtin_amdgcn_sched_barrier(0);
    __builtin_amdgcn_s_barrier();
    __builtin_amdgcn_sched_barrier(0);
  }

  float* outF = (float*)outp;
  unsigned short* outH = (unsigned short*)outp;
  const size_t cb = (size_t)batch * (size_t)sC;
#pragma unroll
  for (int mf = 0; mf < 4; ++mf) {
    int rbase = row0 + wr * 64 + mf * 16 + lg * 4;
#pragma unroll
    for (int nf = 0; nf < 4; ++nf) {
      int c = col0 + wc * 64 + nf * 16 + lr;
      f32x4 v = acc[mf][nf];
#pragma unroll
      for (int q = 0; q < 4; ++q) {
        size_t idx = cb + (size_t)(rbase + q) * N + c;
        float val = v[q] * scale;
        if (mode == EPI_F32)         outF[idx] = val;
        else if (mode == EPI_BF)     outH[idx] = f2bf(val);
        else if (mode == EPI_RELUBF) outH[idx] = f2bf(fmaxf(val, 0.f));
        else                         outH[idx] = f2h(val);
      }
    }
  }
#undef STAGE_A
#undef STAGE_B
}

// ---------------- elementwise / reduction kernels (unchanged) ----------------

__device__ __forceinline__ float wave_sum(float v) {
#pragma unroll
  for (int o = 32; o; o >>= 1) v += __shfl_xor(v, o, 64);
  return v;
}
__device__ __forceinline__ float wave_max(float v) {
#pragma unroll
  for (int o = 32; o; o >>= 1) v = fmaxf(v, __shfl_xor(v, o, 64));
  return v;
}

__global__ __launch_bounds__(256) void cast_bf16(const float* __restrict__ in,
                                                 unsigned short* __restrict__ out, long n) {
  long i = ((long)blockIdx.x * 256 + threadIdx.x) * 4;
  if (i >= n) return;
  float4 v = *(const float4*)&in[i];
  ushort4 o;
  o.x = f2bf(v.x); o.y = f2bf(v.y); o.z = f2bf(v.z); o.w = f2bf(v.w);
  *(ushort4*)&out[i] = o;
}

__global__ __launch_bounds__(256) void transpose_cast(const float* __restrict__ in,
                                                      unsigned short* __restrict__ out,
                                                      int R, int C) {
  __shared__ float tile[32][33];
  int c0 = blockIdx.x * 32, r0 = blockIdx.y * 32;
  int tx = threadIdx.x, ty = threadIdx.y;  // block (32,8)
  for (int i = ty; i < 32; i += 8) tile[i][tx] = in[(size_t)(r0 + i) * C + c0 + tx];
  __syncthreads();
  for (int i = ty; i < 32; i += 8) out[(size_t)(c0 + i) * R + r0 + tx] = f2bf(tile[tx][i]);
}

__global__ __launch_bounds__(256) void transpose_b16(const unsigned short* __restrict__ in,
                                                     unsigned short* __restrict__ out,
                                                     int R, int C) {
  __shared__ unsigned short tile[32][33];
  int c0 = blockIdx.x * 32, r0 = blockIdx.y * 32;
  size_t zb = (size_t)blockIdx.z * R * C;
  int tx = threadIdx.x, ty = threadIdx.y;  // block (32,8)
  for (int i = ty; i < 32; i += 8) tile[i][tx] = in[zb + (size_t)(r0 + i) * C + c0 + tx];
  __syncthreads();
  for (int i = ty; i < 32; i += 8) out[zb + (size_t)(c0 + i) * R + r0 + tx] = tile[tx][i];
}

__global__ __launch_bounds__(256) void softmax_rows(const unsigned short* __restrict__ g,
                                                    unsigned short* __restrict__ wout) {
  __shared__ float red[4];
  int row = blockIdx.x, t = threadIdx.x;
  const unsigned short* gr = g + ((size_t)row << 11) + t * 8;
  ushort4 ua = *(const ushort4*)gr;
  ushort4 ub = *(const ushort4*)(gr + 4);
  float a0 = h2f(ua.x), a1 = h2f(ua.y), a2 = h2f(ua.z), a3 = h2f(ua.w);
  float b0 = h2f(ub.x), b1 = h2f(ub.y), b2 = h2f(ub.z), b3 = h2f(ub.w);
  float mx = fmaxf(fmaxf(fmaxf(a0, a1), fmaxf(a2, a3)),
                   fmaxf(fmaxf(b0, b1), fmaxf(b2, b3)));
  mx = wave_max(mx);
  if ((t & 63) == 0) red[t >> 6] = mx;
  __syncthreads();
  mx = fmaxf(fmaxf(red[0], red[1]), fmaxf(red[2], red[3]));
  float e0 = __expf(a0 - mx), e1 = __expf(a1 - mx), e2 = __expf(a2 - mx), e3 = __expf(a3 - mx);
  float e4 = __expf(b0 - mx), e5 = __expf(b1 - mx), e6 = __expf(b2 - mx), e7 = __expf(b3 - mx);
  float s = ((e0 + e1) + (e2 + e3)) + ((e4 + e5) + (e6 + e7));
  s = wave_sum(s);
  __syncthreads();
  if ((t & 63) == 0) red[t >> 6] = s;
  __syncthreads();
  s = (red[0] + red[1]) + (red[2] + red[3]);
  float inv = 1.0f / s;
  ushort4 o0, o1;
  o0.x = f2bf(e0 * inv); o0.y = f2bf(e1 * inv); o0.z = f2bf(e2 * inv); o0.w = f2bf(e3 * inv);
  o1.x = f2bf(e4 * inv); o1.y = f2bf(e5 * inv); o1.z = f2bf(e6 * inv); o1.w = f2bf(e7 * inv);
  size_t base = ((size_t)row << 11) + t * 8;
  *(ushort4*)&wout[base] = o0;
  *(ushort4*)&wout[base + 4] = o1;
}

__global__ __launch_bounds__(256) void ln_residual_bf(const unsigned short* __restrict__ xb,
                                                      const float* __restrict__ attn,
                                                      unsigned short* __restrict__ outB) {
  __shared__ float red[4];
  int row = blockIdx.x, t = threadIdx.x;
  size_t base = ((size_t)row << 10) + t * 4;
  ushort4 ua = *(const ushort4*)&xb[base];
  float4 vb = *(const float4*)&attn[base];
  float4 v = {bf2f(ua.x) + vb.x, bf2f(ua.y) + vb.y, bf2f(ua.z) + vb.z, bf2f(ua.w) + vb.w};
  float s = (v.x + v.y) + (v.z + v.w);
  float ss = (v.x * v.x + v.y * v.y) + (v.z * v.z + v.w * v.w);
  s = wave_sum(s);
  if ((t & 63) == 0) red[t >> 6] = s;
  __syncthreads();
  s = (red[0] + red[1]) + (red[2] + red[3]);
  ss = wave_sum(ss);
  __syncthreads();
  if ((t & 63) == 0) red[t >> 6] = ss;
  __syncthreads();
  ss = (red[0] + red[1]) + (red[2] + red[3]);
  float mean = s * (1.0f / 1024.0f);
  float var = (ss - s * mean) * (1.0f / 1023.0f);
  float rstd = rsqrtf(var);
  ushort4 ob;
  ob.x = f2bf((v.x - mean) * rstd); ob.y = f2bf((v.y - mean) * rstd);
  ob.z = f2bf((v.z - mean) * rstd); ob.w = f2bf((v.w - mean) * rstd);
  *(ushort4*)&outB[base] = ob;
}

__global__ __launch_bounds__(256) void ln_residual_dot(const unsigned short* __restrict__ h2,
                                                       const unsigned short* __restrict__ post,
                                                       const float* __restrict__ readout,
                                                       float* __restrict__ rowdot) {
  __shared__ float red[4];
  int row = blockIdx.x, t = threadIdx.x;
  size_t base = ((size_t)row << 10) + t * 4;
  ushort4 ua = *(const ushort4*)&h2[base];
  ushort4 ub = *(const ushort4*)&post[base];
  float4 v = {bf2f(ua.x) + bf2f(ub.x), bf2f(ua.y) + bf2f(ub.y),
              bf2f(ua.z) + bf2f(ub.z), bf2f(ua.w) + bf2f(ub.w)};
  float s = (v.x + v.y) + (v.z + v.w);
  float ss = (v.x * v.x + v.y * v.y) + (v.z * v.z + v.w * v.w);
  s = wave_sum(s);
  if ((t & 63) == 0) red[t >> 6] = s;
  __syncthreads();
  s = (red[0] + red[1]) + (red[2] + red[3]);
  ss = wave_sum(ss);
  __syncthreads();
  if ((t & 63) == 0) red[t >> 6] = ss;
  __syncthreads();
  ss = (red[0] + red[1]) + (red[2] + red[3]);
  float mean = s * (1.0f / 1024.0f);
  float var = (ss - s * mean) * (1.0f / 1023.0f);
  float rstd = rsqrtf(var);
  float4 r = *(const float4*)&readout[t * 4];
  float dot = (v.x - mean) * rstd * r.x + (v.y - mean) * rstd * r.y +
              (v.z - mean) * rstd * r.z + (v.w - mean) * rstd * r.w;
  dot = wave_sum(dot);
  __syncthreads();
  if ((t & 63) == 0) red[t >> 6] = dot;
  __syncthreads();
  if (t == 0) rowdot[row] = (red[0] + red[1]) + (red[2] + red[3]);
}

__global__ __launch_bounds__(256) void reduce_out(const float* __restrict__ rowdot,
                                                  float* __restrict__ out) {
  __shared__ float red[4];
  int b = blockIdx.x, t = threadIdx.x;
  float s = 0.f;
  for (int i = t; i < 2048; i += 256) s += rowdot[(size_t)b * 2048 + i];
  s = wave_sum(s);
  if ((t & 63) == 0) red[t >> 6] = s;
  __syncthreads();
  if (t == 0) out[b] = ((red[0] + red[1]) + (red[2] + red[3])) * (1.0f / 65536.0f);
}

extern "C" void kernel_launch(void* const* d_in, const int* in_sizes, int n_in,
                              void* d_out, int out_size, void* d_ws, size_t ws_size,
                              hipStream_t stream) {
  const float* seq     = (const float*)d_in[0];  // [8,2048,768]
  const float* emb     = (const float*)d_in[1];  // [768,1024]
  const float* W1      = (const float*)d_in[2];  // [1024,1024]
  const float* W2      = (const float*)d_in[3];  // [1024,1024]
  const float* readout = (const float*)d_in[4];  // [1024]
  float* out = (float*)d_out;                    // [8]

  char* ws = (char*)d_ws;
  const size_t MB = 1024u * 1024u;
  // aliased layout (same as round 3 — verified):
  unsigned short* x_b    = (unsigned short*)(ws + 0);        // 32MB [G1..LN1]
  unsigned short* h2b    = (unsigned short*)(ws + 0);        // 32MB [FFN2..LN2]
  unsigned short* xT     = (unsigned short*)(ws + 32 * MB);  // 32MB [tr..attnV]
  unsigned short* hrelu  = (unsigned short*)(ws + 32 * MB);  // 32MB [FFN1..FFN2]
  unsigned short* gram   = (unsigned short*)(ws + 64 * MB);  // 64MB f16 [G2..sm]
  float*          attn   = (float*)(ws + 64 * MB);           // 64MB [aV..LN1]
  unsigned short* wts    = (unsigned short*)(ws + 128 * MB); // 64MB [sm..attnV]
  unsigned short* post_b = (unsigned short*)(ws + 128 * MB); // 32MB [LN1..LN2]
  unsigned short* seq_b  = (unsigned short*)(ws + 192 * MB); // 24MB [cast..G1]
  unsigned short* embT   = (unsigned short*)(ws + 216 * MB);
  unsigned short* W1T    = (unsigned short*)(ws + 218 * MB);
  unsigned short* W2T    = (unsigned short*)(ws + 220 * MB);
  float*          rowdot = (float*)(ws + 222 * MB);

  // 1. dtype prep
  cast_bf16<<<12288, 256, 0, stream>>>(seq, seq_b, 12582912L);
  transpose_cast<<<dim3(32, 24), dim3(32, 8), 0, stream>>>(emb, embT, 768, 1024);
  transpose_cast<<<dim3(32, 32), dim3(32, 8), 0, stream>>>(W1, W1T, 1024, 1024);
  transpose_cast<<<dim3(32, 32), dim3(32, 8), 0, stream>>>(W2, W2T, 1024, 1024);

  // 2. x = seq @ emb / sqrt(768)  -> bf16   (grid = 64*8 = 512)
  gemm_bt<<<512, 512, 0, stream>>>(seq_b, embT, 16384, 1024, 768, 1, 0, 0, 0,
                                   0.03608439182435161f, EPI_BF, x_b);

  // 3. xT[b] = x[b]^T
  transpose_b16<<<dim3(32, 64, 8), dim3(32, 8), 0, stream>>>(x_b, xT, 2048, 1024);

  // 4. gram[b] = x[b] @ x[b]^T / 1024 -> f16  (grid = 8*8*16 = 1024)
  gemm_bt<<<1024, 512, 0, stream>>>(x_b, x_b, 2048, 2048, 1024, 8,
                                    2048L * 1024, 2048L * 1024, 2048L * 2048,
                                    1.0f / 1024.0f, EPI_F16, gram);

  // 5. weights = softmax(gram) -> bf16
  softmax_rows<<<16384, 256, 0, stream>>>(gram, wts);

  // 6. attn[b] = weights[b] @ x[b] -> f32  (grid = 8*8*8 = 512)
  gemm_bt<<<512, 512, 0, stream>>>(wts, xT, 2048, 1024, 2048, 8,
                                   2048L * 2048, 1024L * 2048, 2048L * 1024,
                                   1.0f, EPI_F32, attn);

  // 7. post = LN(x + attn) -> bf16
  ln_residual_bf<<<16384, 256, 0, stream>>>(x_b, attn, post_b);

  // 8. FFN (grids 64*8 = 512)
  gemm_bt<<<512, 512, 0, stream>>>(post_b, W1T, 16384, 1024, 1024, 1, 0, 0, 0,
                                   0.03125f, EPI_RELUBF, hrelu);
  gemm_bt<<<512, 512, 0, stream>>>(hrelu, W2T, 16384, 1024, 1024, 1, 0, 0, 0,
                                   0.03125f, EPI_BF, h2b);

  // 9. final LN + pooled readout
  ln_residual_dot<<<16384, 256, 0, stream>>>(h2b, post_b, readout, rowdot);
  reduce_out<<<8, 256, 0, stream>>>(rowdot, out);
}

// Round 5
// 393.903 us; speedup vs baseline: 2.3491x; 1.0929x over previous
//
#include <hip/hip_runtime.h>
#include <hip/hip_bf16.h>

typedef __bf16 bf16x8 __attribute__((ext_vector_type(8)));
typedef float f32x4 __attribute__((ext_vector_type(4)));

__device__ __forceinline__ unsigned short f2bf(float f) {
  union { float f; unsigned u; } x; x.f = f;
  unsigned r = x.u + 0x7fffu + ((x.u >> 16) & 1u);
  return (unsigned short)(r >> 16);
}
__device__ __forceinline__ float bf2f(unsigned short u) {
  union { unsigned u; float f; } x; x.u = (unsigned)u << 16;
  return x.f;
}
__device__ __forceinline__ unsigned short f2h(float f) {
  union { _Float16 h; unsigned short u; } x; x.h = (_Float16)f;
  return x.u;
}
__device__ __forceinline__ float h2f(unsigned short u) {
  union { _Float16 h; unsigned short u; } x; x.u = u;
  return (float)x.h;
}

__device__ __forceinline__ void async_ld16(const void* g, void* l) {
  __builtin_amdgcn_global_load_lds(
      (__attribute__((address_space(1))) void*)const_cast<void*>(g),
      (__attribute__((address_space(3))) void*)l, 16, 0, 0);
}

// ---------------- 256x256 double-buffered pipelined GEMM ----------------
// BM=BN=256, BK=64, 512 threads (8 waves: 2M x 4N), per-wave 128x64 out.
// LDS: 2 buffers x (A 256x64 + B 256x64) bf16 = 128 KB -> 1 block/CU, 8 waves.
// Per K-tile: 2 barriers; counted s_waitcnt vmcnt(8) (loads span a barrier,
// never drained to 0 mid-loop); ds_reads+MFMAs in ONE region (no internal
// barriers) so waves on a SIMD overlap reads with MFMA; setprio around MFMA.
// Swizzle: LDS slot (row, cgrp ^ (row&7)) via pre-swizzled per-lane GLOBAL
// source (linear LDS dest) + same XOR on ds_read addr (round-4 verified: 0
// bank conflicts).
// Race ledger: iter t: [barA: all waves done reading tile t-1] -> issue
// STAGE(buf[(t+1)&1], t+1) (overwrites t-1's buffer: safe) -> vmcnt(8)
// (retires this wave's tile-t loads; 8 of t+1 stay in flight) -> [barB: all
// waves' vmcnt passed => tile t fully in LDS] -> ds_read/MFMA tile t.

#define EPI_F32    0
#define EPI_BF     1
#define EPI_RELUBF 2
#define EPI_F16    3

__global__ __launch_bounds__(512, 2) void gemm_bt(
    const unsigned short* __restrict__ A,   // [nb][M][K] bf16
    const unsigned short* __restrict__ Bt,  // [nb][N][K] bf16
    int M, int N, int K, int nbatch,
    long sA, long sB, long sC,
    float scale, int mode, void* __restrict__ outp)
{
  __shared__ unsigned short lds[65536];  // 2 x (16384 A + 16384 B) elems
  const int t = threadIdx.x;
  const int w = t >> 6, l = t & 63;
  const int lr = l & 15, lg = l >> 4;
  const int wr = w >> 2, wc = w & 3;           // 2 M-waves x 4 N-waves
  const int ntn = N >> 8;                      // N/256
  const int tiles = (M >> 8) * ntn;            // per batch
  const int chunk = (tiles * nbatch) >> 3;
  const int bid = blockIdx.x;
  const int wg = (bid & 7) * chunk + (bid >> 3);
  const int batch = wg / tiles;
  const int rem = wg - batch * tiles;
  const int row0 = (rem / ntn) << 8;
  const int col0 = (rem % ntn) << 8;

  const unsigned short* Ab  = A  + (long)batch * sA;
  const unsigned short* Btb = Bt + (long)batch * sB;

  // staging geometry: thread covers row rsub of each 64-row slab, swizzled src col
  const int rsub = t >> 3;                       // 0..63
  const int cg8  = ((t & 7) ^ (rsub & 7)) << 3;  // swizzled k-offset (elems)
  const long arow = (long)(row0 + rsub) * K;
  const long brow = (long)(col0 + rsub) * K;
  const long rstep = (long)K << 6;               // 64 rows

  const int NT = K >> 6;

#define STAGE(buf, kk0)                                                     \
  {                                                                         \
    const unsigned short* sa = Ab + arow + (kk0) + cg8;                     \
    const unsigned short* sb = Btb + brow + (kk0) + cg8;                    \
    unsigned short* da = (buf) + t * 8;                                     \
    unsigned short* db = (buf) + 16384 + t * 8;                             \
    async_ld16(sa,             da);                                         \
    async_ld16(sa + rstep,     da + 4096);                                  \
    async_ld16(sa + 2 * rstep, da + 8192);                                  \
    async_ld16(sa + 3 * rstep, da + 12288);                                 \
    async_ld16(sb,             db);                                         \
    async_ld16(sb + rstep,     db + 4096);                                  \
    async_ld16(sb + 2 * rstep, db + 8192);                                  \
    async_ld16(sb + 3 * rstep, db + 12288);                                 \
  }

  f32x4 acc[8][4];
#pragma unroll
  for (int m = 0; m < 8; ++m)
#pragma unroll
    for (int n = 0; n < 4; ++n) acc[m][n] = (f32x4){0.f, 0.f, 0.f, 0.f};

  // prologue: stage tile 0 into buf0
  STAGE(lds, 0);
  __builtin_amdgcn_sched_barrier(0);

  for (int tt = 0; tt < NT; ++tt) {
    unsigned short* ldsA = lds + (tt & 1) * 32768;
    unsigned short* ldsB = ldsA + 16384;
    unsigned short* ldsN = lds + ((tt + 1) & 1) * 32768;

    __builtin_amdgcn_s_barrier();              // A: all waves done reading t-1
    __builtin_amdgcn_sched_barrier(0);
    if (tt + 1 < NT) {
      STAGE(ldsN, (tt + 1) << 6);
      __builtin_amdgcn_sched_barrier(0);
      asm volatile("s_waitcnt vmcnt(8)" ::: "memory");   // retire tile t
    } else {
      asm volatile("s_waitcnt vmcnt(0)" ::: "memory");
    }
    __builtin_amdgcn_sched_barrier(0);
    __builtin_amdgcn_s_barrier();              // B: tile t published
    __builtin_amdgcn_sched_barrier(0);

#pragma unroll
    for (int kk = 0; kk < 2; ++kk) {
      bf16x8 af[8], bfr[4];
#pragma unroll
      for (int mf = 0; mf < 8; ++mf) {
        int Ra = wr * 128 + mf * 16 + lr;
        af[mf] = *(const bf16x8*)&ldsA[Ra * 64 + ((kk * 32 + lg * 8) ^ ((Ra & 7) << 3))];
      }
#pragma unroll
      for (int nf = 0; nf < 4; ++nf) {
        int Rb = wc * 64 + nf * 16 + lr;
        bfr[nf] = *(const bf16x8*)&ldsB[Rb * 64 + ((kk * 32 + lg * 8) ^ ((Rb & 7) << 3))];
      }
      __builtin_amdgcn_s_setprio(1);
#pragma unroll
      for (int mf = 0; mf < 8; ++mf)
#pragma unroll
        for (int nf = 0; nf < 4; ++nf)
          acc[mf][nf] = __builtin_amdgcn_mfma_f32_16x16x32_bf16(af[mf], bfr[nf], acc[mf][nf], 0, 0, 0);
      __builtin_amdgcn_s_setprio(0);
    }
    __builtin_amdgcn_sched_barrier(0);
  }

  float* outF = (float*)outp;
  unsigned short* outH = (unsigned short*)outp;
  const size_t cb = (size_t)batch * (size_t)sC;
#pragma unroll
  for (int mf = 0; mf < 8; ++mf) {
    int rbase = row0 + wr * 128 + mf * 16 + lg * 4;
#pragma unroll
    for (int nf = 0; nf < 4; ++nf) {
      int c = col0 + wc * 64 + nf * 16 + lr;
      f32x4 v = acc[mf][nf];
#pragma unroll
      for (int q = 0; q < 4; ++q) {
        size_t idx = cb + (size_t)(rbase + q) * N + c;
        float val = v[q] * scale;
        if (mode == EPI_F32)         outF[idx] = val;
        else if (mode == EPI_BF)     outH[idx] = f2bf(val);
        else if (mode == EPI_RELUBF) outH[idx] = f2bf(fmaxf(val, 0.f));
        else                         outH[idx] = f2h(val);
      }
    }
  }
#undef STAGE
}

// ---------------- elementwise / reduction kernels (unchanged) ----------------

__device__ __forceinline__ float wave_sum(float v) {
#pragma unroll
  for (int o = 32; o; o >>= 1) v += __shfl_xor(v, o, 64);
  return v;
}
__device__ __forceinline__ float wave_max(float v) {
#pragma unroll
  for (int o = 32; o; o >>= 1) v = fmaxf(v, __shfl_xor(v, o, 64));
  return v;
}

__global__ __launch_bounds__(256) void cast_bf16(const float* __restrict__ in,
                                                 unsigned short* __restrict__ out, long n) {
  long i = ((long)blockIdx.x * 256 + threadIdx.x) * 4;
  if (i >= n) return;
  float4 v = *(const float4*)&in[i];
  ushort4 o;
  o.x = f2bf(v.x); o.y = f2bf(v.y); o.z = f2bf(v.z); o.w = f2bf(v.w);
  *(ushort4*)&out[i] = o;
}

__global__ __launch_bounds__(256) void transpose_cast(const float* __restrict__ in,
                                                      unsigned short* __restrict__ out,
                                                      int R, int C) {
  __shared__ float tile[32][33];
  int c0 = blockIdx.x * 32, r0 = blockIdx.y * 32;
  int tx = threadIdx.x, ty = threadIdx.y;  // block (32,8)
  for (int i = ty; i < 32; i += 8) tile[i][tx] = in[(size_t)(r0 + i) * C + c0 + tx];
  __syncthreads();
  for (int i = ty; i < 32; i += 8) out[(size_t)(c0 + i) * R + r0 + tx] = f2bf(tile[tx][i]);
}

__global__ __launch_bounds__(256) void transpose_b16(const unsigned short* __restrict__ in,
                                                     unsigned short* __restrict__ out,
                                                     int R, int C) {
  __shared__ unsigned short tile[32][33];
  int c0 = blockIdx.x * 32, r0 = blockIdx.y * 32;
  size_t zb = (size_t)blockIdx.z * R * C;
  int tx = threadIdx.x, ty = threadIdx.y;  // block (32,8)
  for (int i = ty; i < 32; i += 8) tile[i][tx] = in[zb + (size_t)(r0 + i) * C + c0 + tx];
  __syncthreads();
  for (int i = ty; i < 32; i += 8) out[zb + (size_t)(c0 + i) * R + r0 + tx] = tile[tx][i];
}

__global__ __launch_bounds__(256) void softmax_rows(const unsigned short* __restrict__ g,
                                                    unsigned short* __restrict__ wout) {
  __shared__ float red[4];
  int row = blockIdx.x, t = threadIdx.x;
  const unsigned short* gr = g + ((size_t)row << 11) + t * 8;
  ushort4 ua = *(const ushort4*)gr;
  ushort4 ub = *(const ushort4*)(gr + 4);
  float a0 = h2f(ua.x), a1 = h2f(ua.y), a2 = h2f(ua.z), a3 = h2f(ua.w);
  float b0 = h2f(ub.x), b1 = h2f(ub.y), b2 = h2f(ub.z), b3 = h2f(ub.w);
  float mx = fmaxf(fmaxf(fmaxf(a0, a1), fmaxf(a2, a3)),
                   fmaxf(fmaxf(b0, b1), fmaxf(b2, b3)));
  mx = wave_max(mx);
  if ((t & 63) == 0) red[t >> 6] = mx;
  __syncthreads();
  mx = fmaxf(fmaxf(red[0], red[1]), fmaxf(red[2], red[3]));
  float e0 = __expf(a0 - mx), e1 = __expf(a1 - mx), e2 = __expf(a2 - mx), e3 = __expf(a3 - mx);
  float e4 = __expf(b0 - mx), e5 = __expf(b1 - mx), e6 = __expf(b2 - mx), e7 = __expf(b3 - mx);
  float s = ((e0 + e1) + (e2 + e3)) + ((e4 + e5) + (e6 + e7));
  s = wave_sum(s);
  __syncthreads();
  if ((t & 63) == 0) red[t >> 6] = s;
  __syncthreads();
  s = (red[0] + red[1]) + (red[2] + red[3]);
  float inv = 1.0f / s;
  ushort4 o0, o1;
  o0.x = f2bf(e0 * inv); o0.y = f2bf(e1 * inv); o0.z = f2bf(e2 * inv); o0.w = f2bf(e3 * inv);
  o1.x = f2bf(e4 * inv); o1.y = f2bf(e5 * inv); o1.z = f2bf(e6 * inv); o1.w = f2bf(e7 * inv);
  size_t base = ((size_t)row << 11) + t * 8;
  *(ushort4*)&wout[base] = o0;
  *(ushort4*)&wout[base + 4] = o1;
}

__global__ __launch_bounds__(256) void ln_residual_bf(const unsigned short* __restrict__ xb,
                                                      const float* __restrict__ attn,
                                                      unsigned short* __restrict__ outB) {
  __shared__ float red[4];
  int row = blockIdx.x, t = threadIdx.x;
  size_t base = ((size_t)row << 10) + t * 4;
  ushort4 ua = *(const ushort4*)&xb[base];
  float4 vb = *(const float4*)&attn[base];
  float4 v = {bf2f(ua.x) + vb.x, bf2f(ua.y) + vb.y, bf2f(ua.z) + vb.z, bf2f(ua.w) + vb.w};
  float s = (v.x + v.y) + (v.z + v.w);
  float ss = (v.x * v.x + v.y * v.y) + (v.z * v.z + v.w * v.w);
  s = wave_sum(s);
  if ((t & 63) == 0) red[t >> 6] = s;
  __syncthreads();
  s = (red[0] + red[1]) + (red[2] + red[3]);
  ss = wave_sum(ss);
  __syncthreads();
  if ((t & 63) == 0) red[t >> 6] = ss;
  __syncthreads();
  ss = (red[0] + red[1]) + (red[2] + red[3]);
  float mean = s * (1.0f / 1024.0f);
  float var = (ss - s * mean) * (1.0f / 1023.0f);
  float rstd = rsqrtf(var);
  ushort4 ob;
  ob.x = f2bf((v.x - mean) * rstd); ob.y = f2bf((v.y - mean) * rstd);
  ob.z = f2bf((v.z - mean) * rstd); ob.w = f2bf((v.w - mean) * rstd);
  *(ushort4*)&outB[base] = ob;
}

__global__ __launch_bounds__(256) void ln_residual_dot(const unsigned short* __restrict__ h2,
                                                       const unsigned short* __restrict__ post,
                                                       const float* __restrict__ readout,
                                                       float* __restrict__ rowdot) {
  __shared__ float red[4];
  int row = blockIdx.x, t = threadIdx.x;
  size_t base = ((size_t)row << 10) + t * 4;
  ushort4 ua = *(const ushort4*)&h2[base];
  ushort4 ub = *(const ushort4*)&post[base];
  float4 v = {bf2f(ua.x) + bf2f(ub.x), bf2f(ua.y) + bf2f(ub.y),
              bf2f(ua.z) + bf2f(ub.z), bf2f(ua.w) + bf2f(ub.w)};
  float s = (v.x + v.y) + (v.z + v.w);
  float ss = (v.x * v.x + v.y * v.y) + (v.z * v.z + v.w * v.w);
  s = wave_sum(s);
  if ((t & 63) == 0) red[t >> 6] = s;
  __syncthreads();
  s = (red[0] + red[1]) + (red[2] + red[3]);
  ss = wave_sum(ss);
  __syncthreads();
  if ((t & 63) == 0) red[t >> 6] = ss;
  __syncthreads();
  ss = (red[0] + red[1]) + (red[2] + red[3]);
  float mean = s * (1.0f / 1024.0f);
  float var = (ss - s * mean) * (1.0f / 1023.0f);
  float rstd = rsqrtf(var);
  float4 r = *(const float4*)&readout[t * 4];
  float dot = (v.x - mean) * rstd * r.x + (v.y - mean) * rstd * r.y +
              (v.z - mean) * rstd * r.z + (v.w - mean) * rstd * r.w;
  dot = wave_sum(dot);
  __syncthreads();
  if ((t & 63) == 0) red[t >> 6] = dot;
  __syncthreads();
  if (t == 0) rowdot[row] = (red[0] + red[1]) + (red[2] + red[3]);
}

__global__ __launch_bounds__(256) void reduce_out(const float* __restrict__ rowdot,
                                                  float* __restrict__ out) {
  __shared__ float red[4];
  int b = blockIdx.x, t = threadIdx.x;
  float s = 0.f;
  for (int i = t; i < 2048; i += 256) s += rowdot[(size_t)b * 2048 + i];
  s = wave_sum(s);
  if ((t & 63) == 0) red[t >> 6] = s;
  __syncthreads();
  if (t == 0) out[b] = ((red[0] + red[1]) + (red[2] + red[3])) * (1.0f / 65536.0f);
}

extern "C" void kernel_launch(void* const* d_in, const int* in_sizes, int n_in,
                              void* d_out, int out_size, void* d_ws, size_t ws_size,
                              hipStream_t stream) {
  const float* seq     = (const float*)d_in[0];  // [8,2048,768]
  const float* emb     = (const float*)d_in[1];  // [768,1024]
  const float* W1      = (const float*)d_in[2];  // [1024,1024]
  const float* W2      = (const float*)d_in[3];  // [1024,1024]
  const float* readout = (const float*)d_in[4];  // [1024]
  float* out = (float*)d_out;                    // [8]

  char* ws = (char*)d_ws;
  const size_t MB = 1024u * 1024u;
  // aliased layout (verified rounds 3-4):
  unsigned short* x_b    = (unsigned short*)(ws + 0);        // 32MB [G1..LN1]
  unsigned short* h2b    = (unsigned short*)(ws + 0);        // 32MB [FFN2..LN2]
  unsigned short* xT     = (unsigned short*)(ws + 32 * MB);  // 32MB [tr..attnV]
  unsigned short* hrelu  = (unsigned short*)(ws + 32 * MB);  // 32MB [FFN1..FFN2]
  unsigned short* gram   = (unsigned short*)(ws + 64 * MB);  // 64MB f16 [G2..sm]
  float*          attn   = (float*)(ws + 64 * MB);           // 64MB [aV..LN1]
  unsigned short* wts    = (unsigned short*)(ws + 128 * MB); // 64MB [sm..attnV]
  unsigned short* post_b = (unsigned short*)(ws + 128 * MB); // 32MB [LN1..LN2]
  unsigned short* seq_b  = (unsigned short*)(ws + 192 * MB); // 24MB [cast..G1]
  unsigned short* embT   = (unsigned short*)(ws + 216 * MB);
  unsigned short* W1T    = (unsigned short*)(ws + 218 * MB);
  unsigned short* W2T    = (unsigned short*)(ws + 220 * MB);
  float*          rowdot = (float*)(ws + 222 * MB);

  // 1. dtype prep
  cast_bf16<<<12288, 256, 0, stream>>>(seq, seq_b, 12582912L);
  transpose_cast<<<dim3(32, 24), dim3(32, 8), 0, stream>>>(emb, embT, 768, 1024);
  transpose_cast<<<dim3(32, 32), dim3(32, 8), 0, stream>>>(W1, W1T, 1024, 1024);
  transpose_cast<<<dim3(32, 32), dim3(32, 8), 0, stream>>>(W2, W2T, 1024, 1024);

  // 2. x = seq @ emb / sqrt(768)  -> bf16   (grid = 64*4 = 256)
  gemm_bt<<<256, 512, 0, stream>>>(seq_b, embT, 16384, 1024, 768, 1, 0, 0, 0,
                                   0.03608439182435161f, EPI_BF, x_b);

  // 3. xT[b] = x[b]^T
  transpose_b16<<<dim3(32, 64, 8), dim3(32, 8), 0, stream>>>(x_b, xT, 2048, 1024);

  // 4. gram[b] = x[b] @ x[b]^T / 1024 -> f16  (grid = 8*8*8 = 512)
  gemm_bt<<<512, 512, 0, stream>>>(x_b, x_b, 2048, 2048, 1024, 8,
                                   2048L * 1024, 2048L * 1024, 2048L * 2048,
                                   1.0f / 1024.0f, EPI_F16, gram);

  // 5. weights = softmax(gram) -> bf16
  softmax_rows<<<16384, 256, 0, stream>>>(gram, wts);

  // 6. attn[b] = weights[b] @ x[b] -> f32  (grid = 8*4*8 = 256)
  gemm_bt<<<256, 512, 0, stream>>>(wts, xT, 2048, 1024, 2048, 8,
                                   2048L * 2048, 1024L * 2048, 2048L * 1024,
                                   1.0f, EPI_F32, attn);

  // 7. post = LN(x + attn) -> bf16
  ln_residual_bf<<<16384, 256, 0, stream>>>(x_b, attn, post_b);

  // 8. FFN (grids 64*4 = 256)
  gemm_bt<<<256, 512, 0, stream>>>(post_b, W1T, 16384, 1024, 1024, 1, 0, 0, 0,
                                   0.03125f, EPI_RELUBF, hrelu);
  gemm_bt<<<256, 512, 0, stream>>>(hrelu, W2T, 16384, 1024, 1024, 1, 0, 0, 0,
                                   0.03125f, EPI_BF, h2b);

  // 9. final LN + pooled readout
  ln_residual_dot<<<16384, 256, 0, stream>>>(h2b, post_b, readout, rowdot);
  reduce_out<<<8, 256, 0, stream>>>(rowdot, out);
}